// Round 10
// baseline (569.020 us; speedup 1.0000x reference)
//
#include <hip/hip_runtime.h>

#define DEVI __device__ __forceinline__

typedef __attribute__((ext_vector_type(8))) __bf16 bf16x8;
typedef __attribute__((ext_vector_type(4))) float floatx4;

constexpr int Bsz = 8192;   // batch
constexpr int Hd  = 2048;   // hidden
constexpr int INd = 2048;   // input dim
constexpr int N1  = Bsz * INd;

DEVI unsigned short f2bf_rne(float f) {
  unsigned int u = __float_as_uint(f);
  u += 0x7FFFu + ((u >> 16) & 1u);
  return (unsigned short)(u >> 16);
}

__global__ void cvt4(const float* __restrict__ s0, const float* __restrict__ s1,
                     const float* __restrict__ s2, const float* __restrict__ s3,
                     unsigned short* __restrict__ dst) {
  const float* src = (blockIdx.y == 0) ? s0 : (blockIdx.y == 1) ? s1
                   : (blockIdx.y == 2) ? s2 : s3;
  unsigned short* out = dst + (size_t)blockIdx.y * N1;
  const int nv = N1 / 4;
  for (int i = blockIdx.x * blockDim.x + threadIdx.x; i < nv;
       i += gridDim.x * blockDim.x) {
    float4 v = ((const float4*)src)[i];
    ushort4 o;
    o.x = f2bf_rne(v.x); o.y = f2bf_rne(v.y);
    o.z = f2bf_rne(v.z); o.w = f2bf_rne(v.w);
    ((ushort4*)out)[i] = o;
  }
}

DEVI void gload_lds16(const void* g, void* l) {
  __builtin_amdgcn_global_load_lds(
      (const __attribute__((address_space(1))) void*)g,
      (__attribute__((address_space(3))) void*)l, 16, 0, 0);
}

DEVI float sigm(float x) { return 1.0f / (1.0f + __expf(-x)); }

// 256x256 tile, BK=64, 8 waves (2M x 4N), 16x16x32 MFMA, 0-conflict swizzle,
// 24 ds_read/wave/K-tile, counted vmcnt(4), TWO barriers/K-tile.
// R10: ALL 24 ds_reads front-loaded at tile top. MFMA(0,0) lgkm-waits only
// its 12 oldest reads; the remaining 12 drain in the LDS pipe UNDER the
// first two MFMA clusters; clusters 3-4 run read-free. Same registers as R9
// (all four fragment arrays were already co-live). K-loop unrolled x2 for
// compile-time buffer parity.
// Hazard ledger: S2b/S3 overwrite beta B-h0/A-h1 after mid-BAR; arrival at
// mid-BAR implies A0/B0/A1 reads completed (lgkm-consumed by MFMA(0,0)/(1,0)).
// beta B-h1 (bg1's region) next written at tile t+1's S2a, after tile t's
// final BAR where bg1 was lgkm-consumed. vmcnt: at t-1's W4=vmcnt(4), all of
// tile t's 8 stage-loads are confirmed (newest 4 = t-1's S2b/S3 only).
__global__ __launch_bounds__(512, 2) void lstm_gemm(
    const unsigned short* __restrict__ ws,
    const float* __restrict__ bias,
    const float* __restrict__ c_prev,
    float* __restrict__ out_h,
    float* __restrict__ out_c) {
  __shared__ __align__(16) unsigned short sm[4 * 256 * 64];  // 128 KiB
  char* smc = (char*)sm;

  const unsigned short* xb  = ws;
  const unsigned short* hb  = ws + (size_t)N1;
  const unsigned short* wih = ws + (size_t)2 * N1;
  const unsigned short* whh = ws + (size_t)3 * N1;

  const int tid  = threadIdx.x;
  const int lane = tid & 63;
  const int wid  = tid >> 6;
  const int wm   = wid >> 2, wn = wid & 3;
  const int lr   = lane & 15, lk = lane >> 4;
  const int lr8  = lane >> 3;
  const int swc  = ((lane & 7) ^ lr8) * 8;   // swizzled source chunk (elems)

  // XCD-aware chunked swizzle (FETCH 1.1GB -> 427MB).
  const int wg = blockIdx.x;
  const int x8 = wg & 7;
  const int lc = wg >> 3;
  const int bc = (x8 & 3) * 8 + (lc & 7);             // h-col tile 0..31
  const int rb = ((x8 >> 2) * 16 + (lc >> 3)) * 256;  // batch row base

  // Per-thread stage source offsets (elements), K-tile-independent.
  unsigned int aOff[2][2], bOff[2][2];
#pragma unroll
  for (int h = 0; h < 2; ++h)
#pragma unroll
    for (int j = 0; j < 2; ++j) {
      const int arow = rb + h * 128 + j * 64 + wid * 8 + lr8;
      aOff[h][j] = (unsigned)arow * 2048u + (unsigned)swc;
      const int c  = h * 128 + j * 64 + wid * 8 + lr8;   // block-col index
      const int cf = c >> 4, ce = c & 15;
      const int gate = (cf & 1) | ((cf >> 2) & 2);
      const int hch  = (cf >> 1) & 3;
      const int brow = gate * 2048 + bc * 64 + hch * 16 + ce;
      bOff[h][j] = (unsigned)brow * 2048u + (unsigned)swc;
    }

  floatx4 acc[2][4][2][2];
#pragma unroll
  for (int a = 0; a < 2; ++a)
#pragma unroll
    for (int b = 0; b < 4; ++b)
#pragma unroll
      for (int c = 0; c < 2; ++c)
#pragma unroll
        for (int d = 0; d < 2; ++d)
          acc[a][b][c][d] = (floatx4){0.f, 0.f, 0.f, 0.f};

#define STAGE_A(ts, h) {                                                      \
    const int bs_ = (ts) & 1;                                                 \
    const unsigned short* s_ = (((ts) < 32) ? xb : hb) + (((ts) & 31) * 64);  \
    gload_lds16(s_ + aOff[h][0], smc + bs_ * 32768 + ((h) * 128 + wid * 8) * 128);        \
    gload_lds16(s_ + aOff[h][1], smc + bs_ * 32768 + ((h) * 128 + 64 + wid * 8) * 128); }
#define STAGE_B(ts, h) {                                                      \
    const int bs_ = (ts) & 1;                                                 \
    const unsigned short* s_ = (((ts) < 32) ? wih : whh) + (((ts) & 31) * 64);\
    gload_lds16(s_ + bOff[h][0], smc + 65536 + bs_ * 32768 + ((h) * 128 + wid * 8) * 128);        \
    gload_lds16(s_ + bOff[h][1], smc + 65536 + bs_ * 32768 + ((h) * 128 + 64 + wid * 8) * 128); }

#define LDA(DST, QM)                                                          \
  _Pragma("unroll") for (int mr = 0; mr < 4; ++mr)                            \
    _Pragma("unroll") for (int s = 0; s < 2; ++s) {                           \
      const int row  = (QM) * 128 + wm * 64 + mr * 16 + lr;                   \
      const int phys = (s * 4 + lk) ^ (row & 7);                              \
      DST[mr][s] = *(const bf16x8*)(Ab + row * 128 + phys * 16); }
#define LDB(DST, QN)                                                          \
  _Pragma("unroll") for (int nc = 0; nc < 2; ++nc)                            \
    _Pragma("unroll") for (int s = 0; s < 2; ++s) {                           \
      const int row  = ((QN) * 8 + wn * 2 + nc) * 16 + lr;                    \
      const int phys = (s * 4 + lk) ^ (row & 7);                              \
      DST[nc][s] = *(const bf16x8*)(Bb + row * 128 + phys * 16); }
#define MFMA16(QM, QN, AF, BG)                                                \
  __builtin_amdgcn_s_setprio(1);                                              \
  _Pragma("unroll") for (int mr = 0; mr < 4; ++mr)                            \
    _Pragma("unroll") for (int nc = 0; nc < 2; ++nc)                          \
      _Pragma("unroll") for (int s = 0; s < 2; ++s)                           \
        acc[QM][mr][QN][nc] = __builtin_amdgcn_mfma_f32_16x16x32_bf16(        \
            AF[mr][s], BG[nc][s], acc[QM][mr][QN][nc], 0, 0, 0);              \
  __builtin_amdgcn_s_setprio(0);
#define BAR  asm volatile("s_barrier" ::: "memory")
#define VM4  asm volatile("s_waitcnt vmcnt(4)" ::: "memory")
#define VM0  asm volatile("s_waitcnt vmcnt(0)" ::: "memory")
#define NOP  (void)0

// One K-tile: front-loaded reads, 2 barriers.
//   [R A0(8) B0(4) A1(8) B1(4)] [S1; S2a]
//   MFMA(0,0) MFMA(1,0)  [BAR]
//   [S2b; S3] MFMA(1,1) MFMA(0,1)  W4 [BAR]
#define KTILE(BETA, S1, S2a, S2b, S3, W4) {                                   \
    const char* Ab = smc + (BETA) * 32768;                                    \
    const char* Bb = smc + 65536 + (BETA) * 32768;                            \
    bf16x8 afA[4][2], afB[4][2], bg0[2][2], bg1[2][2];                        \
    LDA(afA, 0); LDB(bg0, 0); LDA(afB, 1); LDB(bg1, 1);                       \
    S1; S2a;                                                                  \
    MFMA16(0, 0, afA, bg0);                                                   \
    MFMA16(1, 0, afB, bg0); BAR;                                              \
    S2b; S3;                                                                  \
    MFMA16(1, 1, afB, bg1);                                                   \
    MFMA16(0, 1, afA, bg1); W4; BAR;                                          \
  }

  // Prologue: tile 0 complete, then tile 1's first halves; full drain once.
  STAGE_A(0, 0); STAGE_B(0, 0); STAGE_A(0, 1); STAGE_B(0, 1);
  STAGE_B(1, 0); STAGE_A(1, 1);
  VM0;
  BAR;

  for (int u = 0; u < 31; ++u) {
    const int t0 = 2 * u;
    KTILE(0, STAGE_A(t0 + 1, 0), STAGE_B(t0 + 1, 1),
          STAGE_B(t0 + 2, 0), STAGE_A(t0 + 2, 1), VM4);
    KTILE(1, STAGE_A(t0 + 2, 0), STAGE_B(t0 + 2, 1),
          STAGE_B(t0 + 3, 0), STAGE_A(t0 + 3, 1), VM4);
  }
  KTILE(0, STAGE_A(63, 0), STAGE_B(63, 1), NOP, NOP, VM0);  // t = 62
  KTILE(1, NOP, NOP, NOP, NOP, NOP);                        // t = 63

  // Epilogue: lane-local LSTM (all 4 gates live in-lane).
  const int hcol = bc * 64 + wn * 16 + lr;
  const float b_i = bias[hcol];
  const float b_f = bias[2048 + hcol];
  const float b_j = bias[4096 + hcol];
  const float b_o = bias[6144 + hcol];
#pragma unroll
  for (int qm = 0; qm < 2; ++qm)
#pragma unroll
    for (int mr = 0; mr < 4; ++mr)
#pragma unroll
      for (int r = 0; r < 4; ++r) {
        const int row = rb + qm * 128 + wm * 64 + mr * 16 + lk * 4 + r;
        const float gi = acc[qm][mr][0][0][r] + b_i;
        const float gf = acc[qm][mr][0][1][r] + b_f;
        const float gj = acc[qm][mr][1][0][r] + b_j;
        const float go = acc[qm][mr][1][1][r] + b_o;
        const float iv = sigm(gi);
        const float fv = sigm(gf);
        const float jv = tanhf(gj);
        const float ov = sigm(go);
        const size_t idx = (size_t)row * 2048 + hcol;
        const float cp = c_prev[idx];
        const float cv = fv * cp + fminf(1.0f - fv, iv) * jv;
        out_h[idx] = ov * tanhf(cv);
        out_c[idx] = cv;
      }
}

extern "C" void kernel_launch(void* const* d_in, const int* in_sizes, int n_in,
                              void* d_out, int out_size, void* d_ws, size_t ws_size,
                              hipStream_t stream) {
  const float* x      = (const float*)d_in[0];
  const float* h_prev = (const float*)d_in[1];
  const float* c_prev = (const float*)d_in[2];
  const float* w_ih   = (const float*)d_in[3];
  const float* w_hh   = (const float*)d_in[4];
  const float* bias   = (const float*)d_in[5];

  float* out_h = (float*)d_out;
  float* out_c = out_h + (size_t)Bsz * Hd;
  unsigned short* wsb = (unsigned short*)d_ws;

  dim3 cgrid(2048, 4);
  cvt4<<<cgrid, 256, 0, stream>>>(x, h_prev, w_ih, w_hh, wsb);

  lstm_gemm<<<1024, 512, 0, stream>>>(wsb, bias, c_prev, out_h, out_c);
}

// Round 11
// 515.196 us; speedup vs baseline: 1.1045x; 1.1045x over previous
//
#include <hip/hip_runtime.h>

#define DEVI __device__ __forceinline__

typedef __attribute__((ext_vector_type(8))) __bf16 bf16x8;
typedef __attribute__((ext_vector_type(4))) float floatx4;

constexpr int Bsz = 8192;   // batch
constexpr int Hd  = 2048;   // hidden
constexpr int INd = 2048;   // input dim
constexpr int N1  = Bsz * INd;

DEVI unsigned short f2bf_rne(float f) {
  unsigned int u = __float_as_uint(f);
  u += 0x7FFFu + ((u >> 16) & 1u);
  return (unsigned short)(u >> 16);
}

__global__ void cvt4(const float* __restrict__ s0, const float* __restrict__ s1,
                     const float* __restrict__ s2, const float* __restrict__ s3,
                     unsigned short* __restrict__ dst) {
  const float* src = (blockIdx.y == 0) ? s0 : (blockIdx.y == 1) ? s1
                   : (blockIdx.y == 2) ? s2 : s3;
  unsigned short* out = dst + (size_t)blockIdx.y * N1;
  const int nv = N1 / 4;
  for (int i = blockIdx.x * blockDim.x + threadIdx.x; i < nv;
       i += gridDim.x * blockDim.x) {
    float4 v = ((const float4*)src)[i];
    ushort4 o;
    o.x = f2bf_rne(v.x); o.y = f2bf_rne(v.y);
    o.z = f2bf_rne(v.z); o.w = f2bf_rne(v.w);
    ((ushort4*)out)[i] = o;
  }
}

DEVI void gload_lds16(const void* g, void* l) {
  __builtin_amdgcn_global_load_lds(
      (const __attribute__((address_space(1))) void*)g,
      (__attribute__((address_space(3))) void*)l, 16, 0, 0);
}

DEVI float sigm(float x) { return 1.0f / (1.0f + __expf(-x)); }
DEVI float tanh_fast(float x) { return 1.0f - 2.0f / (1.0f + __expf(2.0f * x)); }

// 256x256 tile, BK=64, 8 waves (2M x 4N), 16x16x32 MFMA, 0-conflict swizzle,
// 24 ds_read/wave/K-tile, counted vmcnt(4), TWO barriers/K-tile (R9 schedule).
// R11: PRECOMPUTED LDS READ BASES. For both A and B fragment reads,
// row&7 == lr&7, so phys = (s*4+lk)^(lr&7) is loop-invariant. All reads use
// one of 8 per-lane base pointers (beta x s x {A,B}; wm*8192 / wn*4096
// folded in) + a COMPILE-TIME byte offset (QM*16384 + mr*2048 <= 22528,
// QN*16384 + nc*2048 <= 18432, both < 64 KiB ds offset field) ->
// ds_read_b128 vBase offset:CONST, zero VALU per read.
__global__ __launch_bounds__(512, 2) void lstm_gemm(
    const unsigned short* __restrict__ ws,
    const float* __restrict__ bias,
    const float* __restrict__ c_prev,
    float* __restrict__ out_h,
    float* __restrict__ out_c) {
  __shared__ __align__(16) unsigned short sm[4 * 256 * 64];  // 128 KiB
  char* smc = (char*)sm;

  const unsigned short* xb  = ws;
  const unsigned short* hb  = ws + (size_t)N1;
  const unsigned short* wih = ws + (size_t)2 * N1;
  const unsigned short* whh = ws + (size_t)3 * N1;

  const int tid  = threadIdx.x;
  const int lane = tid & 63;
  const int wid  = tid >> 6;
  const int wm   = wid >> 2, wn = wid & 3;
  const int lr   = lane & 15, lk = lane >> 4;
  const int lr8  = lane >> 3;
  const int swc  = ((lane & 7) ^ lr8) * 8;   // swizzled source chunk (elems)

  // XCD-aware chunked swizzle (FETCH 1.1GB -> 427MB).
  const int wg = blockIdx.x;
  const int x8 = wg & 7;
  const int lc = wg >> 3;
  const int bc = (x8 & 3) * 8 + (lc & 7);             // h-col tile 0..31
  const int rb = ((x8 >> 2) * 16 + (lc >> 3)) * 256;  // batch row base

  // Per-thread stage source offsets (elements), K-tile-independent.
  unsigned int aOff[2][2], bOff[2][2];
#pragma unroll
  for (int h = 0; h < 2; ++h)
#pragma unroll
    for (int j = 0; j < 2; ++j) {
      const int arow = rb + h * 128 + j * 64 + wid * 8 + lr8;
      aOff[h][j] = (unsigned)arow * 2048u + (unsigned)swc;
      const int c  = h * 128 + j * 64 + wid * 8 + lr8;   // block-col index
      const int cf = c >> 4, ce = c & 15;
      const int gate = (cf & 1) | ((cf >> 2) & 2);
      const int hch  = (cf >> 1) & 3;
      const int brow = gate * 2048 + bc * 64 + hch * 16 + ce;
      bOff[h][j] = (unsigned)brow * 2048u + (unsigned)swc;
    }

  // Precomputed per-lane LDS read base pointers (loop-invariant).
  const int rA = lr & 7;
  const char* pA[2][2];  // [beta][s]
  const char* pB[2][2];
#pragma unroll
  for (int be = 0; be < 2; ++be)
#pragma unroll
    for (int s = 0; s < 2; ++s) {
      const int phys = (s * 4 + lk) ^ rA;
      pA[be][s] = smc + be * 32768 + wm * 8192 + lr * 128 + phys * 16;
      pB[be][s] = smc + 65536 + be * 32768 + wn * 4096 + lr * 128 + phys * 16;
    }

  floatx4 acc[2][4][2][2];
#pragma unroll
  for (int a = 0; a < 2; ++a)
#pragma unroll
    for (int b = 0; b < 4; ++b)
#pragma unroll
      for (int c = 0; c < 2; ++c)
#pragma unroll
        for (int d = 0; d < 2; ++d)
          acc[a][b][c][d] = (floatx4){0.f, 0.f, 0.f, 0.f};

#define STAGE_A(ts, h) {                                                      \
    const int bs_ = (ts) & 1;                                                 \
    const unsigned short* s_ = (((ts) < 32) ? xb : hb) + (((ts) & 31) * 64);  \
    gload_lds16(s_ + aOff[h][0], smc + bs_ * 32768 + ((h) * 128 + wid * 8) * 128);        \
    gload_lds16(s_ + aOff[h][1], smc + bs_ * 32768 + ((h) * 128 + 64 + wid * 8) * 128); }
#define STAGE_B(ts, h) {                                                      \
    const int bs_ = (ts) & 1;                                                 \
    const unsigned short* s_ = (((ts) < 32) ? wih : whh) + (((ts) & 31) * 64);\
    gload_lds16(s_ + bOff[h][0], smc + 65536 + bs_ * 32768 + ((h) * 128 + wid * 8) * 128);        \
    gload_lds16(s_ + bOff[h][1], smc + 65536 + bs_ * 32768 + ((h) * 128 + 64 + wid * 8) * 128); }

// Fragment reads: base pointer + compile-time offset only.
#define LDA(DST, BETA, QM)                                                    \
  _Pragma("unroll") for (int mr = 0; mr < 4; ++mr)                            \
    _Pragma("unroll") for (int s = 0; s < 2; ++s)                             \
      DST[mr][s] = *(const bf16x8*)(pA[BETA][s] + ((QM) * 16384 + mr * 2048));
#define LDB(DST, BETA, QN)                                                    \
  _Pragma("unroll") for (int nc = 0; nc < 2; ++nc)                            \
    _Pragma("unroll") for (int s = 0; s < 2; ++s)                             \
      DST[nc][s] = *(const bf16x8*)(pB[BETA][s] + ((QN) * 16384 + nc * 2048));
#define MFMA16(QM, QN, AF, BG)                                                \
  __builtin_amdgcn_s_setprio(1);                                              \
  _Pragma("unroll") for (int mr = 0; mr < 4; ++mr)                            \
    _Pragma("unroll") for (int nc = 0; nc < 2; ++nc)                          \
      _Pragma("unroll") for (int s = 0; s < 2; ++s)                           \
        acc[QM][mr][QN][nc] = __builtin_amdgcn_mfma_f32_16x16x32_bf16(        \
            AF[mr][s], BG[nc][s], acc[QM][mr][QN][nc], 0, 0, 0);              \
  __builtin_amdgcn_s_setprio(0);
#define BAR  asm volatile("s_barrier" ::: "memory")
#define VM4  asm volatile("s_waitcnt vmcnt(4)" ::: "memory")
#define VM0  asm volatile("s_waitcnt vmcnt(0)" ::: "memory")
#define NOP  (void)0

// R9 schedule: ring (0,0)(1,0)(1,1)(0,1), TWO barriers/K-tile, W4 after the
// last (register-only) MFMA cluster. Hazard ledger unchanged from R9.
#define KTILE(BETA, S1, S2a, S2b, S3, W4) {                                   \
    bf16x8 afA[4][2], afB[4][2], bg0[2][2], bg1[2][2];                        \
    LDA(afA, BETA, 0); LDB(bg0, BETA, 0); S1;                                 \
    MFMA16(0, 0, afA, bg0);                                                   \
    LDA(afB, BETA, 1); S2a;                                                   \
    MFMA16(1, 0, afB, bg0); BAR;                                              \
    LDB(bg1, BETA, 1); S2b; S3;                                               \
    MFMA16(1, 1, afB, bg1);                                                   \
    MFMA16(0, 1, afA, bg1); W4; BAR;                                          \
  }

  // Prologue: tile 0 complete, then tile 1's first halves; full drain once.
  STAGE_A(0, 0); STAGE_B(0, 0); STAGE_A(0, 1); STAGE_B(0, 1);
  STAGE_B(1, 0); STAGE_A(1, 1);
  VM0;
  BAR;

  for (int u = 0; u < 31; ++u) {
    const int t0 = 2 * u;
    KTILE(0, STAGE_A(t0 + 1, 0), STAGE_B(t0 + 1, 1),
          STAGE_B(t0 + 2, 0), STAGE_A(t0 + 2, 1), VM4);
    KTILE(1, STAGE_A(t0 + 2, 0), STAGE_B(t0 + 2, 1),
          STAGE_B(t0 + 3, 0), STAGE_A(t0 + 3, 1), VM4);
  }
  KTILE(0, STAGE_A(63, 0), STAGE_B(63, 1), NOP, NOP, VM0);  // t = 62
  KTILE(1, NOP, NOP, NOP, NOP, NOP);                        // t = 63

  // Epilogue: lane-local LSTM (all 4 gates live in-lane).
  const int hcol = bc * 64 + wn * 16 + lr;
  const float b_i = bias[hcol];
  const float b_f = bias[2048 + hcol];
  const float b_j = bias[4096 + hcol];
  const float b_o = bias[6144 + hcol];
#pragma unroll
  for (int qm = 0; qm < 2; ++qm)
#pragma unroll
    for (int mr = 0; mr < 4; ++mr)
#pragma unroll
      for (int r = 0; r < 4; ++r) {
        const int row = rb + qm * 128 + wm * 64 + mr * 16 + lk * 4 + r;
        const float gi = acc[qm][mr][0][0][r] + b_i;
        const float gf = acc[qm][mr][0][1][r] + b_f;
        const float gj = acc[qm][mr][1][0][r] + b_j;
        const float go = acc[qm][mr][1][1][r] + b_o;
        const float iv = sigm(gi);
        const float fv = sigm(gf);
        const float jv = tanh_fast(gj);
        const float ov = sigm(go);
        const size_t idx = (size_t)row * 2048 + hcol;
        const float cp = c_prev[idx];
        const float cv = fv * cp + fminf(1.0f - fv, iv) * jv;
        out_h[idx] = ov * tanh_fast(cv);
        out_c[idx] = cv;
      }
}

extern "C" void kernel_launch(void* const* d_in, const int* in_sizes, int n_in,
                              void* d_out, int out_size, void* d_ws, size_t ws_size,
                              hipStream_t stream) {
  const float* x      = (const float*)d_in[0];
  const float* h_prev = (const float*)d_in[1];
  const float* c_prev = (const float*)d_in[2];
  const float* w_ih   = (const float*)d_in[3];
  const float* w_hh   = (const float*)d_in[4];
  const float* bias   = (const float*)d_in[5];

  float* out_h = (float*)d_out;
  float* out_c = out_h + (size_t)Bsz * Hd;
  unsigned short* wsb = (unsigned short*)d_ws;

  dim3 cgrid(2048, 4);
  cvt4<<<cgrid, 256, 0, stream>>>(x, h_prev, w_ih, w_hh, wsb);

  lstm_gemm<<<1024, 512, 0, stream>>>(wsb, bias, c_prev, out_h, out_c);
}